// Round 3
// baseline (120.557 us; speedup 1.0000x reference)
//
#include <hip/hip_runtime.h>
#include <hip/hip_cooperative_groups.h>
#include <math.h>

// Problem constants (B=8, T=1024, H=640, N_PHONE=230, N_PHONEME=96)
#define NH 640
#define NP 230
#define NM 96
#define NROWS 8192
#define MAXL 32
#define NSTEP 20            // K-steps of 32
#define MBLK 32             // rows per block
#define NBLOCKS (NROWS / MBLK)   // 256 -> 1 block/CU (cooperative, co-resident)
#define PFB 8               // B-prefetch depth (K-steps) issued after grid sync
#define FRAGS_PER_BLK 80    // 20480 B-frags / 256 blocks

// ws layout (byte offsets)
#define OFF_CNT  0
#define OFF_CSR  4096
#define OFF_B    65536      // wsB2: 20480 frags * 16 B = 327,680 B

typedef __bf16 bf16_t;
typedef bf16_t bf16x8 __attribute__((ext_vector_type(8)));
typedef float floatx4 __attribute__((ext_vector_type(4)));

namespace cg = cooperative_groups;

// fp32 -> bf16 round-to-nearest-even
static __device__ __forceinline__ unsigned short f2b(float f) {
    unsigned u = __float_as_uint(f);
    u += 0x7fffu + ((u >> 16) & 1u);
    return (unsigned short)(u >> 16);
}

// ---------------- Single cooperative kernel:
//  P0: issue prep loads (f2p share, mapping) FIRST, then enc loads — vmcnt retires
//      in order, so prep consumes complete at L3 latency while enc HBM fetch flies.
//  P1: B-retile share (80 frags/block -> wsB2), CSR build (blocks 0..95).
//  P2: stage A: fp32->bf16 frag-major LDS (consumes enc loads, BW-bound ~3.3us).
//  grid.sync()  — all blocks' wsB2/csr writes visible.
//  P3: csr re-read (oldest in queue), B prefetch, barrier-free MFMA K-loop.
//  P4: seg-max + log_softmax epilogue (cnt/csr from LDS).
// Wave wv owns a 32-col group (2 B-frags/step) across all 32 rows; every B
// fragment is loaded exactly once per block.
__global__ __launch_bounds__(512, 2)
void fused_all_kernel(const float* __restrict__ enc,
                      const float* __restrict__ f2p,
                      const float* __restrict__ mapping,
                      unsigned short* __restrict__ wsB2,
                      int* __restrict__ cnt,
                      int* __restrict__ csr,
                      float* __restrict__ out) {
    // A frags: slot f = (s*2 + rh)*64 + lane, 8 bf16 each -> 2560*16 = 40960 B.
    // Reused as phone[32][257] floats (32896 B) in the epilogue.
    __shared__ __align__(16) unsigned short sA[2560 * 8];
    __shared__ int scnt[NM];
    __shared__ int scsr[NM * MAXL];      // 12288 B
    float (*phone)[257] = (float (*)[257])sA;

    const int tid  = threadIdx.x;
    const int lane = tid & 63;
    const int wv   = tid >> 6;          // 0..7 = column group (32 cols each)
    const int m16  = lane & 15;
    const int quad = lane >> 4;
    const int b    = blockIdx.x;
    const int row0 = b * MBLK;

    // ---- P0a: f2p loads for my B-frag share (oldest in vmcnt queue)
    const bool doB = (tid < FRAGS_PER_BLK);
    const int  pg  = b * FRAGS_PER_BLK + tid;
    float pf[8];
    int pn = 0;
    if (doB) {
        int m16p = pg & 15;
        int qd   = (pg >> 4) & 3;
        int ct   = (pg >> 6) & 15;
        int sp   = pg >> 10;
        pn = ct * 16 + m16p;
        int k0 = sp * 32 + qd * 8;
        #pragma unroll
        for (int j = 0; j < 8; ++j)
            pf[j] = (pn < NP) ? f2p[(size_t)(k0 + j) * NP + pn] : 0.0f;
    }

    // ---- P0b: mapping loads for CSR build (blocks 0..95, wave 0)
    const bool doC = (b < NM) && (tid < 64);
    float mv[4];
    if (doC) {
        #pragma unroll
        for (int c = 0; c < 4; ++c) {
            int p = c * 64 + lane;
            mv[c] = (p < NP) ? mapping[b * NP + p] : 0.0f;
        }
    }

    // ---- P0c: enc loads (newest — their completion is not on prep's path)
    float4 areg[10];
    #pragma unroll
    for (int i = 0; i < 10; ++i)
        areg[i] = *(const float4*)(enc + (size_t)row0 * NH + i * 2048 + tid * 4);

    // ---- P1a: B-retile share -> wsB2
    if (doB) {
        unsigned short v[8];
        #pragma unroll
        for (int j = 0; j < 8; ++j) v[j] = f2b(pf[j]);
        *(uint4*)(wsB2 + (size_t)pg * 8) = *(const uint4*)v;
    }

    // ---- P1b: CSR build for phoneme b
    if (doC) {
        int base = 0;
        #pragma unroll
        for (int c = 0; c < 4; ++c) {
            unsigned long long mask = __ballot(mv[c] > 0.0f);
            if (mv[c] > 0.0f) {
                int idx = base + __popcll(mask & ((1ull << lane) - 1ull));
                if (idx < MAXL) csr[b * MAXL + idx] = c * 64 + lane;
            }
            base += __popcll(mask);
        }
        if (lane == 0) cnt[b] = base < MAXL ? base : MAXL;
    }

    // ---- P2: stage A: convert + frag-major LDS write
    #pragma unroll
    for (int i = 0; i < 10; ++i) {
        int F = i * 2048 + tid * 4;
        int row = F / 640;
        int k   = F - row * 640;
        int s  = k >> 5;
        int q  = (k & 31) >> 3;
        int j0 = k & 7;                  // 0 or 4
        unsigned short v[4];
        v[0] = f2b(areg[i].x); v[1] = f2b(areg[i].y);
        v[2] = f2b(areg[i].z); v[3] = f2b(areg[i].w);
        int soff = ((s * 2 + (row >> 4)) * 64 + q * 16 + (row & 15)) * 8 + j0;
        *(uint2*)(sA + soff) = *(const uint2*)v;
    }

    cg::this_grid().sync();   // wsB2 + csr/cnt visible device-wide; sA block-visible

    // ---- P3: csr/cnt re-read (oldest in queue -> never forces a B drain)
    int creg[6];
    #pragma unroll
    for (int j = 0; j < 6; ++j) creg[j] = csr[tid + j * 512];
    int cc = (tid < NM) ? cnt[tid] : 0;

    const unsigned short* bptr = wsB2 + ((size_t)(wv * 2) * 64 + lane) * 8;
    uint4 bpre[2 * PFB];
    #pragma unroll
    for (int s = 0; s < PFB; ++s) {
        bpre[2 * s + 0] = *(const uint4*)(bptr + ((size_t)s * 16 + 0) * 64 * 8);
        bpre[2 * s + 1] = *(const uint4*)(bptr + ((size_t)s * 16 + 1) * 64 * 8);
    }

    floatx4 acc00 = {0.f,0.f,0.f,0.f}, acc01 = acc00, acc10 = acc00, acc11 = acc00;
    const unsigned short* aptr = sA + (size_t)lane * 8;

    #pragma unroll
    for (int s = 0; s < NSTEP; ++s) {
        uint4 a0 = *(const uint4*)(aptr + (size_t)(s * 2 + 0) * 64 * 8);
        uint4 a1 = *(const uint4*)(aptr + (size_t)(s * 2 + 1) * 64 * 8);
        uint4 b0, b1;
        if (s < PFB) {
            b0 = bpre[2 * s + 0];
            b1 = bpre[2 * s + 1];
        } else {
            b0 = *(const uint4*)(bptr + ((size_t)s * 16 + 0) * 64 * 8);
            b1 = *(const uint4*)(bptr + ((size_t)s * 16 + 1) * 64 * 8);
        }
        bf16x8 A0 = __builtin_bit_cast(bf16x8, a0);
        bf16x8 A1 = __builtin_bit_cast(bf16x8, a1);
        bf16x8 B0 = __builtin_bit_cast(bf16x8, b0);
        bf16x8 B1 = __builtin_bit_cast(bf16x8, b1);
        acc00 = __builtin_amdgcn_mfma_f32_16x16x32_bf16(A0, B0, acc00, 0, 0, 0);
        acc01 = __builtin_amdgcn_mfma_f32_16x16x32_bf16(A0, B1, acc01, 0, 0, 0);
        acc10 = __builtin_amdgcn_mfma_f32_16x16x32_bf16(A1, B0, acc10, 0, 0, 0);
        acc11 = __builtin_amdgcn_mfma_f32_16x16x32_bf16(A1, B1, acc11, 0, 0, 0);
    }

    __syncthreads();   // A-LDS fully consumed; safe to overwrite with phone[][]

    // C/D layout: col = lane&15, row = quad*4 + reg
    const float scale = 0.03952847075210474f;  // 1/sqrt(640)
    #pragma unroll
    for (int i = 0; i < 4; ++i) {
        int r = quad * 4 + i;
        phone[r     ][wv * 32 +  0 + m16] = acc00[i] * scale;
        phone[r     ][wv * 32 + 16 + m16] = acc01[i] * scale;
        phone[r + 16][wv * 32 +  0 + m16] = acc10[i] * scale;
        phone[r + 16][wv * 32 + 16 + m16] = acc11[i] * scale;
    }
    // spill csr/cnt registers to LDS for the epilogue
    #pragma unroll
    for (int j = 0; j < 6; ++j) scsr[tid + j * 512] = creg[j];
    if (tid < NM) scnt[tid] = cc;
    __syncthreads();

    // ---- P4: seg-max + log_softmax: 16 threads per row (512 = 32 rows x 16)
    const int r   = tid >> 4;
    const int l16 = tid & 15;
    float pmv[6];
    float mx = -INFINITY;
    #pragma unroll
    for (int j = 0; j < 6; ++j) {
        int m = l16 + j * 16;
        int c = scnt[m];
        const int* lst = scsr + m * MAXL;
        float best = -INFINITY;
        for (int jj = 0; jj < c; ++jj) best = fmaxf(best, phone[r][lst[jj]]);
        pmv[j] = best;
        mx = fmaxf(mx, best);
    }
    #pragma unroll
    for (int d = 1; d < 16; d <<= 1) mx = fmaxf(mx, __shfl_xor(mx, d));
    float s = 0.f;
    #pragma unroll
    for (int j = 0; j < 6; ++j) s += __expf(pmv[j] - mx);
    #pragma unroll
    for (int d = 1; d < 16; d <<= 1) s += __shfl_xor(s, d);
    const float lse = mx + __logf(s);
    #pragma unroll
    for (int j = 0; j < 6; ++j)
        out[(size_t)(row0 + r) * NM + l16 + j * 16] = pmv[j] - lse;
}

extern "C" void kernel_launch(void* const* d_in, const int* in_sizes, int n_in,
                              void* d_out, int out_size, void* d_ws, size_t ws_size,
                              hipStream_t stream) {
    const float* enc     = (const float*)d_in[0];   // (8,1024,640) f32
    const float* f2p     = (const float*)d_in[1];   // (640,230) f32
    const float* mapping = (const float*)d_in[2];   // (96,230) f32
    float* out = (float*)d_out;                     // (8,1024,96) f32

    char* ws = (char*)d_ws;
    int* cnt = (int*)(ws + OFF_CNT);
    int* csr = (int*)(ws + OFF_CSR);
    unsigned short* wsB2 = (unsigned short*)(ws + OFF_B);

    void* args[] = {&enc, &f2p, &mapping, &wsB2, &cnt, &csr, &out};
    hipLaunchCooperativeKernel((const void*)fused_all_kernel,
                               dim3(NBLOCKS), dim3(512), args, 0, stream);
}

// Round 4
// 80.819 us; speedup vs baseline: 1.4917x; 1.4917x over previous
//
#include <hip/hip_runtime.h>
#include <math.h>

// Problem constants (B=8, T=1024, H=640, N_PHONE=230, N_PHONEME=96)
#define NH 640
#define NP 230
#define NM 96
#define NROWS 8192
#define MAXL 32
#define NSTEP 20            // K-steps of 32
#define MBLK 32             // rows per block
#define NBLOCKS (NROWS / MBLK)   // 256 -> 1 block/CU
#define PFB 14              // B-prefetch K-steps issued before sync1 (rest after)

// ws layout (byte offsets)
#define OFF_CNT  0
#define OFF_CSR  4096
#define OFF_B    65536      // wsB2: 20480 frags * 16 B = 327,680 B

typedef __bf16 bf16_t;
typedef bf16_t bf16x8 __attribute__((ext_vector_type(8)));
typedef float floatx4 __attribute__((ext_vector_type(4)));

// fp32 -> bf16 round-to-nearest-even
static __device__ __forceinline__ unsigned short f2b(float f) {
    unsigned u = __float_as_uint(f);
    u += 0x7fffu + ((u >> 16) & 1u);
    return (unsigned short)(u >> 16);
}

// ---------------- Prep: CSR build (blocks 0..23) + B retile (blocks 24..103)
// B frag g = (s*16+ct)*64+lane holds B^T[n=ct*16+(lane&15)][k=s*32+(lane>>4)*8+j]
__global__ __launch_bounds__(256)
void prep_kernel(const float* __restrict__ f2p,
                 const float* __restrict__ mapping,
                 int* __restrict__ cnt, int* __restrict__ csr,
                 unsigned short* __restrict__ wsB2) {
    const int b = blockIdx.x;
    const int tid = threadIdx.x;
    if (b < 24) {
        int wave = b * 4 + (tid >> 6);
        int lane = tid & 63;
        if (wave >= NM) return;
        int base = 0;
        #pragma unroll
        for (int c = 0; c < 4; ++c) {
            int p = c * 64 + lane;
            float v = (p < NP) ? mapping[wave * NP + p] : 0.0f;
            unsigned long long mask = __ballot(v > 0.0f);
            if (v > 0.0f) {
                int idx = base + __popcll(mask & ((1ull << lane) - 1ull));
                if (idx < MAXL) csr[wave * MAXL + idx] = p;
            }
            base += __popcll(mask);
        }
        if (lane == 0) cnt[wave] = base < MAXL ? base : MAXL;
    } else {
        int g = (b - 24) * 256 + tid;          // < 20480
        int m16  = g & 15;
        int quad = (g >> 4) & 3;
        int ct   = (g >> 6) & 15;
        int s    = g >> 10;
        int n = ct * 16 + m16;
        int k0 = s * 32 + quad * 8;
        unsigned short v[8];
        #pragma unroll
        for (int j = 0; j < 8; ++j)
            v[j] = (n < NP) ? f2b(f2p[(size_t)(k0 + j) * NP + n]) : (unsigned short)0;
        *(uint4*)(wsB2 + (size_t)g * 8) = *(const uint4*)v;
    }
}

// ---------------- Main: split-K pipelined A staging (half0 staged -> MFMA on
// half0 overlaps half1's HBM fetch), all-register B prefetch, fused epilogue.
// 512 thr (8 waves): wave wv owns a 32-col group (2 B-frags/step) across all
// 32 rows (2 A-frags/step, 4 accumulators); every B fragment loaded once/block.
__global__ __launch_bounds__(512, 2)
void fused_phonetics_kernel(const float* __restrict__ enc,
                            const unsigned short* __restrict__ wsB2,
                            const int* __restrict__ cnt,
                            const int* __restrict__ csr,
                            float* __restrict__ out) {
    // A frags: slot f = (s*2 + rh)*64 + lane, 8 bf16 each -> 2560*16 = 40960 B.
    // Reused as phone[32][257] floats (32896 B) in the epilogue.
    __shared__ __align__(16) unsigned short sA[2560 * 8];
    __shared__ int scnt[NM];
    __shared__ int scsr[NM * MAXL];      // 12288 B
    float (*phone)[257] = (float (*)[257])sA;

    const int tid  = threadIdx.x;
    const int lane = tid & 63;
    const int wv   = tid >> 6;          // 0..7 = column group (32 cols each)
    const int m16  = lane & 15;
    const int quad = lane >> 4;
    const int row0 = blockIdx.x * MBLK;

    // ---- issue csr/cnt FIRST (oldest in vmcnt queue -> their LDS stash waits
    // only on themselves, ~L2 latency, never on enc/B)
    int creg[6];
    #pragma unroll
    for (int j = 0; j < 6; ++j) creg[j] = csr[tid + j * 512];
    int cc = (tid < NM) ? cnt[tid] : 0;

    // ---- enc loads, k-split halves: half h = 32 rows x fp32 k in [h*320,(h+1)*320)
    // flat byte idx G within the 32x1280B submatrix; contiguous per row -> coalesced
    float4 areg0[5], areg1[5];
    #pragma unroll
    for (int i = 0; i < 5; ++i) {
        int G = i * 8192 + tid * 16;
        int row = G / 1280;
        int cb4 = (G - row * 1280) >> 2;     // fp32 col within half, 0..319
        areg0[i] = *(const float4*)(enc + (size_t)(row0 + row) * NH + cb4);
    }
    #pragma unroll
    for (int i = 0; i < 5; ++i) {
        int G = i * 8192 + tid * 16;
        int row = G / 1280;
        int cb4 = (G - row * 1280) >> 2;
        areg1[i] = *(const float4*)(enc + (size_t)(row0 + row) * NH + 320 + cb4);
    }

    // ---- B prefetch, steps 0..PFB-1 (L2-resident wsB2)
    const unsigned short* bptr = wsB2 + ((size_t)(wv * 2) * 64 + lane) * 8;
    uint4 bpre[2 * NSTEP];
    #pragma unroll
    for (int s = 0; s < PFB; ++s) {
        bpre[2 * s + 0] = *(const uint4*)(bptr + ((size_t)s * 16 + 0) * 64 * 8);
        bpre[2 * s + 1] = *(const uint4*)(bptr + ((size_t)s * 16 + 1) * 64 * 8);
    }

    // ---- stash csr/cnt to LDS (waits only the oldest loads)
    #pragma unroll
    for (int j = 0; j < 6; ++j) scsr[tid + j * 512] = creg[j];
    if (tid < NM) scnt[tid] = cc;

    // ---- convert + store half0 (waits enc-half0 retire; half1 still in flight)
    #pragma unroll
    for (int i = 0; i < 5; ++i) {
        int G = i * 8192 + tid * 16;
        int row = G / 1280;
        int cb4 = (G - row * 1280) >> 2;
        int k = cb4;                     // half 0
        int s  = k >> 5;
        int q  = (k & 31) >> 3;
        int j0 = k & 7;                  // 0 or 4
        unsigned short v[4];
        v[0] = f2b(areg0[i].x); v[1] = f2b(areg0[i].y);
        v[2] = f2b(areg0[i].z); v[3] = f2b(areg0[i].w);
        int soff = ((s * 2 + (row >> 4)) * 64 + q * 16 + (row & 15)) * 8 + j0;
        *(uint2*)(sA + soff) = *(const uint2*)v;
    }
    __syncthreads();

    // ---- issue remaining B prefetch (regs disjoint from first-half K-loop)
    #pragma unroll
    for (int s = PFB; s < NSTEP; ++s) {
        bpre[2 * s + 0] = *(const uint4*)(bptr + ((size_t)s * 16 + 0) * 64 * 8);
        bpre[2 * s + 1] = *(const uint4*)(bptr + ((size_t)s * 16 + 1) * 64 * 8);
    }

    floatx4 acc00 = {0.f,0.f,0.f,0.f}, acc01 = acc00, acc10 = acc00, acc11 = acc00;
    const unsigned short* aptr = sA + (size_t)lane * 8;

    // ---- K-steps 0..9 on half0 (overlaps enc-half1 HBM fetch)
    #pragma unroll
    for (int s = 0; s < 10; ++s) {
        uint4 a0 = *(const uint4*)(aptr + (size_t)(s * 2 + 0) * 64 * 8);
        uint4 a1 = *(const uint4*)(aptr + (size_t)(s * 2 + 1) * 64 * 8);
        bf16x8 A0 = __builtin_bit_cast(bf16x8, a0);
        bf16x8 A1 = __builtin_bit_cast(bf16x8, a1);
        bf16x8 B0 = __builtin_bit_cast(bf16x8, bpre[2 * s + 0]);
        bf16x8 B1 = __builtin_bit_cast(bf16x8, bpre[2 * s + 1]);
        acc00 = __builtin_amdgcn_mfma_f32_16x16x32_bf16(A0, B0, acc00, 0, 0, 0);
        acc01 = __builtin_amdgcn_mfma_f32_16x16x32_bf16(A0, B1, acc01, 0, 0, 0);
        acc10 = __builtin_amdgcn_mfma_f32_16x16x32_bf16(A1, B0, acc10, 0, 0, 0);
        acc11 = __builtin_amdgcn_mfma_f32_16x16x32_bf16(A1, B1, acc11, 0, 0, 0);
    }

    // ---- convert + store half1 (waits enc-half1; B-tail is newer -> not waited)
    #pragma unroll
    for (int i = 0; i < 5; ++i) {
        int G = i * 8192 + tid * 16;
        int row = G / 1280;
        int cb4 = (G - row * 1280) >> 2;
        int k = 320 + cb4;               // half 1
        int s  = k >> 5;
        int q  = (k & 31) >> 3;
        int j0 = k & 7;
        unsigned short v[4];
        v[0] = f2b(areg1[i].x); v[1] = f2b(areg1[i].y);
        v[2] = f2b(areg1[i].z); v[3] = f2b(areg1[i].w);
        int soff = ((s * 2 + (row >> 4)) * 64 + q * 16 + (row & 15)) * 8 + j0;
        *(uint2*)(sA + soff) = *(const uint2*)v;
    }
    __syncthreads();

    // ---- K-steps 10..19 on half1
    #pragma unroll
    for (int s = 10; s < NSTEP; ++s) {
        uint4 a0 = *(const uint4*)(aptr + (size_t)(s * 2 + 0) * 64 * 8);
        uint4 a1 = *(const uint4*)(aptr + (size_t)(s * 2 + 1) * 64 * 8);
        bf16x8 A0 = __builtin_bit_cast(bf16x8, a0);
        bf16x8 A1 = __builtin_bit_cast(bf16x8, a1);
        bf16x8 B0 = __builtin_bit_cast(bf16x8, bpre[2 * s + 0]);
        bf16x8 B1 = __builtin_bit_cast(bf16x8, bpre[2 * s + 1]);
        acc00 = __builtin_amdgcn_mfma_f32_16x16x32_bf16(A0, B0, acc00, 0, 0, 0);
        acc01 = __builtin_amdgcn_mfma_f32_16x16x32_bf16(A0, B1, acc01, 0, 0, 0);
        acc10 = __builtin_amdgcn_mfma_f32_16x16x32_bf16(A1, B0, acc10, 0, 0, 0);
        acc11 = __builtin_amdgcn_mfma_f32_16x16x32_bf16(A1, B1, acc11, 0, 0, 0);
    }

    __syncthreads();   // A-LDS fully consumed; safe to overwrite with phone[][]

    // C/D layout: col = lane&15, row = quad*4 + reg
    const float scale = 0.03952847075210474f;  // 1/sqrt(640)
    #pragma unroll
    for (int i = 0; i < 4; ++i) {
        int r = quad * 4 + i;
        phone[r     ][wv * 32 +  0 + m16] = acc00[i] * scale;
        phone[r     ][wv * 32 + 16 + m16] = acc01[i] * scale;
        phone[r + 16][wv * 32 +  0 + m16] = acc10[i] * scale;
        phone[r + 16][wv * 32 + 16 + m16] = acc11[i] * scale;
    }
    __syncthreads();

    // ---- seg-max + log_softmax: 16 threads per row (512 = 32 rows x 16)
    const int r   = tid >> 4;
    const int l16 = tid & 15;
    float pmv[6];
    float mx = -INFINITY;
    #pragma unroll
    for (int j = 0; j < 6; ++j) {
        int m = l16 + j * 16;
        int c = scnt[m];
        const int* lst = scsr + m * MAXL;
        float best = -INFINITY;
        for (int jj = 0; jj < c; ++jj) best = fmaxf(best, phone[r][lst[jj]]);
        pmv[j] = best;
        mx = fmaxf(mx, best);
    }
    #pragma unroll
    for (int d = 1; d < 16; d <<= 1) mx = fmaxf(mx, __shfl_xor(mx, d));
    float s = 0.f;
    #pragma unroll
    for (int j = 0; j < 6; ++j) s += __expf(pmv[j] - mx);
    #pragma unroll
    for (int d = 1; d < 16; d <<= 1) s += __shfl_xor(s, d);
    const float lse = mx + __logf(s);
    #pragma unroll
    for (int j = 0; j < 6; ++j)
        out[(size_t)(row0 + r) * NM + l16 + j * 16] = pmv[j] - lse;
}

extern "C" void kernel_launch(void* const* d_in, const int* in_sizes, int n_in,
                              void* d_out, int out_size, void* d_ws, size_t ws_size,
                              hipStream_t stream) {
    const float* enc     = (const float*)d_in[0];   // (8,1024,640) f32
    const float* f2p     = (const float*)d_in[1];   // (640,230) f32
    const float* mapping = (const float*)d_in[2];   // (96,230) f32
    float* out = (float*)d_out;                     // (8,1024,96) f32

    char* ws = (char*)d_ws;
    int* cnt = (int*)(ws + OFF_CNT);
    int* csr = (int*)(ws + OFF_CSR);
    unsigned short* wsB2 = (unsigned short*)(ws + OFF_B);

    prep_kernel<<<104, 256, 0, stream>>>(f2p, mapping, cnt, csr, wsB2);
    fused_phonetics_kernel<<<NBLOCKS, 512, 0, stream>>>(enc, wsB2, cnt, csr, out);
}